// Round 1
// baseline (7871.666 us; speedup 1.0000x reference)
//
#include <hip/hip_runtime.h>

typedef unsigned short u16;
typedef unsigned int   u32;
typedef __attribute__((ext_vector_type(4))) float  f32x4;
typedef __attribute__((ext_vector_type(8))) __bf16 bf16x8;
typedef __attribute__((ext_vector_type(8))) short  s16x8;
typedef __attribute__((ext_vector_type(4))) unsigned short u16x4;

#define DEVFN __device__ __forceinline__

DEVFN float bf2f(u16 u) {
    u32 v = ((u32)u) << 16;
    return __builtin_bit_cast(float, v);
}
DEVFN u16 f2bf(float f) {   // round-to-nearest-even
    u32 u = __builtin_bit_cast(u32, f);
    u32 r = u + 0x7FFFu + ((u >> 16) & 1u);
    return (u16)(r >> 16);
}

// ---------------- embedding: x[row, :] = tok_emb[idx[row], :] + pos_emb[row%T, :]
__global__ __launch_bounds__(256) void embed_k(const int* __restrict__ idx,
                                               const float* __restrict__ tok,
                                               const float* __restrict__ pos,
                                               float* __restrict__ x)
{
    int i   = blockIdx.x * 256 + threadIdx.x;   // over 8192*256 float4 groups
    int row = i >> 8;
    int c   = (i & 255) << 2;
    int t   = row & 1023;
    int tk  = idx[row];
    float4 a = *(const float4*)&tok[(size_t)tk * 1024 + c];
    float4 p = *(const float4*)&pos[(size_t)t * 1024 + c];
    float4 r; r.x = a.x + p.x; r.y = a.y + p.y; r.z = a.z + p.z; r.w = a.w + p.w;
    *(float4*)&x[(size_t)row * 1024 + c] = r;
}

// ---------------- fp32 [K,N] -> bf16 [N,K] transpose (weights)
__global__ __launch_bounds__(256) void transpose_k(const float* __restrict__ W,
                                                   u16* __restrict__ Wt, int K, int N)
{
    __shared__ float tile[32][33];
    int n0 = blockIdx.x * 32, k0 = blockIdx.y * 32;
    int xx = threadIdx.x, ty = threadIdx.y;      // block (32,8)
#pragma unroll
    for (int yy = 0; yy < 4; ++yy) {
        int y = ty + yy * 8;
        tile[y][xx] = W[(size_t)(k0 + y) * N + n0 + xx];
    }
    __syncthreads();
#pragma unroll
    for (int yy = 0; yy < 4; ++yy) {
        int y = ty + yy * 8;
        Wt[(size_t)(n0 + y) * K + k0 + xx] = f2bf(tile[xx][y]);
    }
}

// ---------------- LayerNorm: fp32 in -> bf16 out, C=1024, one block per row
__global__ __launch_bounds__(256) void ln_k(const float* __restrict__ x,
                                            const float* __restrict__ g,
                                            const float* __restrict__ b,
                                            u16* __restrict__ out)
{
    const int row = blockIdx.x, tid = threadIdx.x;
    const float4 v = *(const float4*)&x[(size_t)row * 1024 + tid * 4];
    __shared__ float red[8];
    float s = v.x + v.y + v.z + v.w;
#pragma unroll
    for (int off = 32; off > 0; off >>= 1) s += __shfl_down(s, off);
    const int lane = tid & 63, wv = tid >> 6;
    if (lane == 0) red[wv] = s;
    __syncthreads();
    const float mu = (red[0] + red[1] + red[2] + red[3]) * (1.0f / 1024.0f);
    const float dx = v.x - mu, dy = v.y - mu, dz = v.z - mu, dw = v.w - mu;
    float s2 = dx * dx + dy * dy + dz * dz + dw * dw;
#pragma unroll
    for (int off = 32; off > 0; off >>= 1) s2 += __shfl_down(s2, off);
    if (lane == 0) red[4 + wv] = s2;
    __syncthreads();
    const float var = (red[4] + red[5] + red[6] + red[7]) * (1.0f / 1024.0f);
    const float rs  = rsqrtf(var + 1e-5f);
    const float4 gv = *(const float4*)&g[tid * 4];
    const float4 bv = *(const float4*)&b[tid * 4];
    u16x4 o;
    o.x = f2bf(dx * rs * gv.x + bv.x);
    o.y = f2bf(dy * rs * gv.y + bv.y);
    o.z = f2bf(dz * rs * gv.z + bv.z);
    o.w = f2bf(dw * rs * gv.w + bv.w);
    *(u16x4*)&out[(size_t)row * 1024 + tid * 4] = o;
}

// ---------------- bf16 MFMA GEMM:  C[M,N] = A[M,K] @ Bt[N,K]^T (+epilogue)
// MODE 0: Ob = bf16(acc)                      (q/k/v proj, no bias)
// MODE 1: RES += acc + bias                   (residual adds, fp32)
// MODE 2: Ob = bf16(relu(acc + bias))         (ffn1)
// MODE 3: Of = acc + bias                     (head, fp32 out)
// M fixed at 8192. 128x128 tile, BK=32, 256 threads = 4 waves (2x2 of 64x64).
template <int MODE>
__global__ __launch_bounds__(256) void gemm_bt(const u16* __restrict__ A,
                                               const u16* __restrict__ Bt,
                                               const float* __restrict__ bias,
                                               float* __restrict__ RES,
                                               u16* __restrict__ Ob,
                                               float* __restrict__ Of,
                                               int N, int K)
{
    __shared__ __align__(16) u16 As[128 * 32];
    __shared__ __align__(16) u16 Bs[128 * 32];
    const int tid  = threadIdx.x;
    const int lane = tid & 63, wave = tid >> 6;
    const int wr = wave >> 1, wc = wave & 1;
    const int l15 = lane & 15, l4 = lane >> 4;
    const int m0 = blockIdx.y * 128, n0 = blockIdx.x * 128;

    f32x4 acc[4][4];
    const f32x4 zz = {0.f, 0.f, 0.f, 0.f};
#pragma unroll
    for (int i = 0; i < 4; ++i)
#pragma unroll
        for (int j = 0; j < 4; ++j) acc[i][j] = zz;

    for (int k0 = 0; k0 < K; k0 += 32) {
        // stage A and Bt tiles (linear 16B chunks: chunk c -> row c>>2, quarter c&3)
        {
            int c = tid, row = c >> 2, q = c & 3;
            *(s16x8*)&As[c * 8] = *(const s16x8*)&A[(size_t)(m0 + row) * K + k0 + q * 8];
            *(s16x8*)&Bs[c * 8] = *(const s16x8*)&Bt[(size_t)(n0 + row) * K + k0 + q * 8];
            c = tid + 256; row = c >> 2; q = c & 3;
            *(s16x8*)&As[c * 8] = *(const s16x8*)&A[(size_t)(m0 + row) * K + k0 + q * 8];
            *(s16x8*)&Bs[c * 8] = *(const s16x8*)&Bt[(size_t)(n0 + row) * K + k0 + q * 8];
        }
        __syncthreads();
        s16x8 af[4], bw[4];
#pragma unroll
        for (int i = 0; i < 4; ++i)
            af[i] = *(const s16x8*)&As[(wr * 64 + i * 16 + l15) * 32 + l4 * 8];
#pragma unroll
        for (int j = 0; j < 4; ++j)
            bw[j] = *(const s16x8*)&Bs[(wc * 64 + j * 16 + l15) * 32 + l4 * 8];
#pragma unroll
        for (int i = 0; i < 4; ++i)
#pragma unroll
            for (int j = 0; j < 4; ++j)
                acc[i][j] = __builtin_amdgcn_mfma_f32_16x16x32_bf16(
                    __builtin_bit_cast(bf16x8, af[i]),
                    __builtin_bit_cast(bf16x8, bw[j]), acc[i][j], 0, 0, 0);
        __syncthreads();
    }

    // epilogue; C/D layout: col = lane&15, row = (lane>>4)*4 + reg  [HW-verified]
#pragma unroll
    for (int i = 0; i < 4; ++i) {
        const int rb = m0 + wr * 64 + i * 16 + l4 * 4;
#pragma unroll
        for (int j = 0; j < 4; ++j) {
            const int col = n0 + wc * 64 + j * 16 + l15;
            const float bval = (MODE == 0) ? 0.0f : bias[col];
#pragma unroll
            for (int r = 0; r < 4; ++r) {
                const size_t o = (size_t)(rb + r) * N + col;
                const float v = acc[i][j][r];
                if (MODE == 0)      Ob[o] = f2bf(v);
                else if (MODE == 1) RES[o] += v + bval;
                else if (MODE == 2) Ob[o] = f2bf(fmaxf(v + bval, 0.0f));
                else                Of[o] = v + bval;
            }
        }
    }
}

// ---------------- flash attention (fp32 compute on bf16 q/k/v), causal
// grid (T/32, B*H), block 256. thread -> (qr = tid>>3 in 0..31, dg = tid&7 -> dims dg*8..+8)
__global__ __launch_bounds__(256) void attn_k(const u16* __restrict__ Qg,
                                              const u16* __restrict__ Kg,
                                              const u16* __restrict__ Vg,
                                              u16* __restrict__ Og)
{
    const int qt = blockIdx.x;          // q tile
    const int bh = blockIdx.y;
    const int b  = bh >> 4, h = bh & 15;
    const int tid = threadIdx.x;
    const int qr = tid >> 3, dg = tid & 7;
    __shared__ __align__(16) float Qs[32][68];
    __shared__ __align__(16) float Ks[32][68];
    __shared__ __align__(16) float Vs[32][68];
    __shared__ float Ps[32][33];

    const int q0 = qt * 32;
    {
        const u16* src = Qg + ((size_t)(b * 1024 + q0 + qr)) * 1024 + h * 64 + dg * 8;
        s16x8 v = *(const s16x8*)src;
#pragma unroll
        for (int e = 0; e < 8; ++e) Qs[qr][dg * 8 + e] = bf2f((u16)v[e]) * 0.125f;
    }
    float m = -3.0e38f, l = 0.0f;
    float o[8] = {0.f, 0.f, 0.f, 0.f, 0.f, 0.f, 0.f, 0.f};

    for (int kt = 0; kt <= qt; ++kt) {
        __syncthreads();   // prev iteration done reading Ks/Vs/Ps
        {
            const size_t rowb = ((size_t)(b * 1024 + kt * 32 + qr)) * 1024 + h * 64 + dg * 8;
            s16x8 kv = *(const s16x8*)&Kg[rowb];
            s16x8 vv = *(const s16x8*)&Vg[rowb];
#pragma unroll
            for (int e = 0; e < 8; ++e) {
                Ks[qr][dg * 8 + e] = bf2f((u16)kv[e]);
                Vs[qr][dg * 8 + e] = bf2f((u16)vv[e]);
            }
        }
        __syncthreads();
        float s0 = 0.f, s1 = 0.f, s2 = 0.f, s3 = 0.f;
        const int kc = dg * 4;
#pragma unroll
        for (int d4 = 0; d4 < 16; ++d4) {
            const float4 qv = *(const float4*)&Qs[qr][d4 * 4];
            const float4 k0v = *(const float4*)&Ks[kc + 0][d4 * 4];
            const float4 k1v = *(const float4*)&Ks[kc + 1][d4 * 4];
            const float4 k2v = *(const float4*)&Ks[kc + 2][d4 * 4];
            const float4 k3v = *(const float4*)&Ks[kc + 3][d4 * 4];
            s0 += qv.x * k0v.x + qv.y * k0v.y + qv.z * k0v.z + qv.w * k0v.w;
            s1 += qv.x * k1v.x + qv.y * k1v.y + qv.z * k1v.z + qv.w * k1v.w;
            s2 += qv.x * k2v.x + qv.y * k2v.y + qv.z * k2v.z + qv.w * k2v.w;
            s3 += qv.x * k3v.x + qv.y * k3v.y + qv.z * k3v.z + qv.w * k3v.w;
        }
        if (kt == qt) {     // causal mask on diagonal tile (k index kc+c vs q index qr)
            if (kc + 0 > qr) s0 = -3.0e38f;
            if (kc + 1 > qr) s1 = -3.0e38f;
            if (kc + 2 > qr) s2 = -3.0e38f;
            if (kc + 3 > qr) s3 = -3.0e38f;
        }
        float mloc = fmaxf(fmaxf(s0, s1), fmaxf(s2, s3));
#pragma unroll
        for (int off = 1; off < 8; off <<= 1) mloc = fmaxf(mloc, __shfl_xor(mloc, off));
        const float mnew = fmaxf(m, mloc);
        const float p0 = __expf(s0 - mnew), p1 = __expf(s1 - mnew);
        const float p2 = __expf(s2 - mnew), p3 = __expf(s3 - mnew);
        float psum = p0 + p1 + p2 + p3;
#pragma unroll
        for (int off = 1; off < 8; off <<= 1) psum += __shfl_xor(psum, off);
        const float alpha = __expf(m - mnew);
        l = l * alpha + psum;
        m = mnew;
#pragma unroll
        for (int e = 0; e < 8; ++e) o[e] *= alpha;
        Ps[qr][kc + 0] = p0; Ps[qr][kc + 1] = p1;
        Ps[qr][kc + 2] = p2; Ps[qr][kc + 3] = p3;
        __syncthreads();
#pragma unroll 8
        for (int kk = 0; kk < 32; ++kk) {
            const float pv = Ps[qr][kk];
            const float4 va = *(const float4*)&Vs[kk][dg * 8];
            const float4 vb = *(const float4*)&Vs[kk][dg * 8 + 4];
            o[0] += pv * va.x; o[1] += pv * va.y; o[2] += pv * va.z; o[3] += pv * va.w;
            o[4] += pv * vb.x; o[5] += pv * vb.y; o[6] += pv * vb.z; o[7] += pv * vb.w;
        }
    }
    const float inv = 1.0f / l;
    s16x8 ov;
#pragma unroll
    for (int e = 0; e < 8; ++e) ov[e] = (short)f2bf(o[e] * inv);
    *(s16x8*)&Og[((size_t)(b * 1024 + q0 + qr)) * 1024 + h * 64 + dg * 8] = ov;
}

// ---------------- orchestration
extern "C" void kernel_launch(void* const* d_in, const int* in_sizes, int n_in,
                              void* d_out, int out_size, void* d_ws, size_t ws_size,
                              hipStream_t stream)
{
    (void)in_sizes; (void)n_in; (void)out_size; (void)ws_size;
    const int*   idx  = (const int*)  d_in[0];
    const float* tok  = (const float*)d_in[1];
    const float* pos  = (const float*)d_in[2];
    const float* Wq   = (const float*)d_in[3];
    const float* Wk   = (const float*)d_in[4];
    const float* Wv   = (const float*)d_in[5];
    const float* Wo   = (const float*)d_in[6];
    const float* bo   = (const float*)d_in[7];
    const float* ln1g = (const float*)d_in[8];
    const float* ln1b = (const float*)d_in[9];
    const float* ln2g = (const float*)d_in[10];
    const float* ln2b = (const float*)d_in[11];
    const float* W1   = (const float*)d_in[12];
    const float* b1   = (const float*)d_in[13];
    const float* W2   = (const float*)d_in[14];
    const float* b2   = (const float*)d_in[15];
    const float* lnfg = (const float*)d_in[16];
    const float* lnfb = (const float*)d_in[17];
    const float* Wh   = (const float*)d_in[18];
    const float* bh   = (const float*)d_in[19];

    char* p = (char*)d_ws;
    float* x = (float*)p;  p += (size_t)8192 * 1024 * 4;
    u16* h   = (u16*)p;    p += (size_t)8192 * 1024 * 2;
    u16* qb  = (u16*)p;    p += (size_t)8192 * 1024 * 2;
    u16* kb  = (u16*)p;    p += (size_t)8192 * 1024 * 2;
    u16* vb  = (u16*)p;    p += (size_t)8192 * 1024 * 2;
    u16* ab  = (u16*)p;    p += (size_t)8192 * 1024 * 2;
    u16* fb  = (u16*)p;    p += (size_t)8192 * 4096 * 2;
    u16* wqT = (u16*)p;    p += (size_t)1024 * 1024 * 2;
    u16* wkT = (u16*)p;    p += (size_t)1024 * 1024 * 2;
    u16* wvT = (u16*)p;    p += (size_t)1024 * 1024 * 2;
    u16* woT = (u16*)p;    p += (size_t)1024 * 1024 * 2;
    u16* w1T = (u16*)p;    p += (size_t)1024 * 4096 * 2;
    u16* w2T = (u16*)p;    p += (size_t)4096 * 1024 * 2;
    u16* whT = (u16*)p;    p += (size_t)1024 * 256 * 2;

    const dim3 tb(32, 8);
    embed_k<<<8192, 256, 0, stream>>>(idx, tok, pos, x);
    for (int l = 0; l < 6; ++l) {
        transpose_k<<<dim3(32, 32),  tb, 0, stream>>>(Wq + (size_t)l * 1048576, wqT, 1024, 1024);
        transpose_k<<<dim3(32, 32),  tb, 0, stream>>>(Wk + (size_t)l * 1048576, wkT, 1024, 1024);
        transpose_k<<<dim3(32, 32),  tb, 0, stream>>>(Wv + (size_t)l * 1048576, wvT, 1024, 1024);
        transpose_k<<<dim3(32, 32),  tb, 0, stream>>>(Wo + (size_t)l * 1048576, woT, 1024, 1024);
        transpose_k<<<dim3(128, 32), tb, 0, stream>>>(W1 + (size_t)l * 4194304, w1T, 1024, 4096);
        transpose_k<<<dim3(32, 128), tb, 0, stream>>>(W2 + (size_t)l * 4194304, w2T, 4096, 1024);

        ln_k<<<8192, 256, 0, stream>>>(x, ln1g + l * 1024, ln1b + l * 1024, h);
        gemm_bt<0><<<dim3(8, 64),  256, 0, stream>>>(h, wqT, nullptr, nullptr, qb, nullptr, 1024, 1024);
        gemm_bt<0><<<dim3(8, 64),  256, 0, stream>>>(h, wkT, nullptr, nullptr, kb, nullptr, 1024, 1024);
        gemm_bt<0><<<dim3(8, 64),  256, 0, stream>>>(h, wvT, nullptr, nullptr, vb, nullptr, 1024, 1024);
        attn_k<<<dim3(32, 128), 256, 0, stream>>>(qb, kb, vb, ab);
        gemm_bt<1><<<dim3(8, 64),  256, 0, stream>>>(ab, woT, bo + l * 1024, x, nullptr, nullptr, 1024, 1024);
        ln_k<<<8192, 256, 0, stream>>>(x, ln2g + l * 1024, ln2b + l * 1024, h);
        gemm_bt<2><<<dim3(32, 64), 256, 0, stream>>>(h, w1T, b1 + l * 4096, nullptr, fb, nullptr, 4096, 1024);
        gemm_bt<1><<<dim3(8, 64),  256, 0, stream>>>(fb, w2T, b2 + l * 1024, x, nullptr, nullptr, 1024, 4096);
    }
    transpose_k<<<dim3(8, 32), tb, 0, stream>>>(Wh, whT, 1024, 256);
    ln_k<<<8192, 256, 0, stream>>>(x, lnfg, lnfb, h);
    gemm_bt<3><<<dim3(2, 64), 256, 0, stream>>>(h, whT, bh, nullptr, nullptr, (float*)d_out, 256, 1024);
}

// Round 2
// 3234.329 us; speedup vs baseline: 2.4338x; 2.4338x over previous
//
#include <hip/hip_runtime.h>

typedef unsigned short u16;
typedef unsigned int   u32;
typedef __attribute__((ext_vector_type(4))) float  f32x4;
typedef __attribute__((ext_vector_type(8))) __bf16 bf16x8;
typedef __attribute__((ext_vector_type(8))) short  s16x8;
typedef __attribute__((ext_vector_type(4))) unsigned short u16x4;

#define DEVFN __device__ __forceinline__

DEVFN float bf2f(u16 u) {
    u32 v = ((u32)u) << 16;
    return __builtin_bit_cast(float, v);
}
DEVFN u16 f2bf(float f) {   // round-to-nearest-even
    u32 u = __builtin_bit_cast(u32, f);
    u32 r = u + 0x7FFFu + ((u >> 16) & 1u);
    return (u16)(r >> 16);
}

// async global->LDS, 16B per lane. LDS dest must be linear in lane order.
DEVFN void gload16(const void* g, void* l) {
    __builtin_amdgcn_global_load_lds(
        (const __attribute__((address_space(1))) void*)g,
        (__attribute__((address_space(3))) void*)l, 16, 0, 0);
}

// ---------------- embedding: x[row, :] = tok_emb[idx[row], :] + pos_emb[row%T, :]
__global__ __launch_bounds__(256) void embed_k(const int* __restrict__ idx,
                                               const float* __restrict__ tok,
                                               const float* __restrict__ pos,
                                               float* __restrict__ x)
{
    int i   = blockIdx.x * 256 + threadIdx.x;
    int row = i >> 8;
    int c   = (i & 255) << 2;
    int t   = row & 1023;
    int tk  = idx[row];
    float4 a = *(const float4*)&tok[(size_t)tk * 1024 + c];
    float4 p = *(const float4*)&pos[(size_t)t * 1024 + c];
    float4 r; r.x = a.x + p.x; r.y = a.y + p.y; r.z = a.z + p.z; r.w = a.w + p.w;
    *(float4*)&x[(size_t)row * 1024 + c] = r;
}

// ---------------- fp32 [K,N] -> bf16 [N,K] transpose (weights)
__global__ __launch_bounds__(256) void transpose_k(const float* __restrict__ W,
                                                   u16* __restrict__ Wt, int K, int N)
{
    __shared__ float tile[32][33];
    int n0 = blockIdx.x * 32, k0 = blockIdx.y * 32;
    int xx = threadIdx.x, ty = threadIdx.y;      // block (32,8)
#pragma unroll
    for (int yy = 0; yy < 4; ++yy) {
        int y = ty + yy * 8;
        tile[y][xx] = W[(size_t)(k0 + y) * N + n0 + xx];
    }
    __syncthreads();
#pragma unroll
    for (int yy = 0; yy < 4; ++yy) {
        int y = ty + yy * 8;
        Wt[(size_t)(n0 + y) * K + k0 + xx] = f2bf(tile[xx][y]);
    }
}

// ---------------- LayerNorm: fp32 in -> bf16 out, C=1024, one block per row
__global__ __launch_bounds__(256) void ln_k(const float* __restrict__ x,
                                            const float* __restrict__ g,
                                            const float* __restrict__ b,
                                            u16* __restrict__ out)
{
    const int row = blockIdx.x, tid = threadIdx.x;
    const float4 v = *(const float4*)&x[(size_t)row * 1024 + tid * 4];
    __shared__ float red[8];
    float s = v.x + v.y + v.z + v.w;
#pragma unroll
    for (int off = 32; off > 0; off >>= 1) s += __shfl_down(s, off);
    const int lane = tid & 63, wv = tid >> 6;
    if (lane == 0) red[wv] = s;
    __syncthreads();
    const float mu = (red[0] + red[1] + red[2] + red[3]) * (1.0f / 1024.0f);
    const float dx = v.x - mu, dy = v.y - mu, dz = v.z - mu, dw = v.w - mu;
    float s2 = dx * dx + dy * dy + dz * dz + dw * dw;
#pragma unroll
    for (int off = 32; off > 0; off >>= 1) s2 += __shfl_down(s2, off);
    if (lane == 0) red[4 + wv] = s2;
    __syncthreads();
    const float var = (red[4] + red[5] + red[6] + red[7]) * (1.0f / 1024.0f);
    const float rs  = rsqrtf(var + 1e-5f);
    const float4 gv = *(const float4*)&g[tid * 4];
    const float4 bv = *(const float4*)&b[tid * 4];
    u16x4 o;
    o.x = f2bf(dx * rs * gv.x + bv.x);
    o.y = f2bf(dy * rs * gv.y + bv.y);
    o.z = f2bf(dz * rs * gv.z + bv.z);
    o.w = f2bf(dw * rs * gv.w + bv.w);
    *(u16x4*)&out[(size_t)row * 1024 + tid * 4] = o;
}

// ---------------- bf16 MFMA GEMM:  C[M,N] = A[M,K] @ Bt[N,K]^T (+epilogue)
// MODE 0: Ob = bf16(acc); 1: RES += acc+bias; 2: Ob = bf16(relu(acc+bias)); 3: Of = acc+bias
// 128x128 tile, BK=32, 256 threads = 4 waves (2x2 of 64x64). global_load_lds staging.
template <int MODE>
__global__ __launch_bounds__(256) void gemm_bt(const u16* __restrict__ A,
                                               const u16* __restrict__ Bt,
                                               const float* __restrict__ bias,
                                               float* __restrict__ RES,
                                               u16* __restrict__ Ob,
                                               float* __restrict__ Of,
                                               int N, int K)
{
    __shared__ __align__(16) u16 As[128 * 32];
    __shared__ __align__(16) u16 Bs[128 * 32];
    const int tid  = threadIdx.x;
    const int lane = tid & 63, wave = tid >> 6;
    const int wr = wave >> 1, wc = wave & 1;
    const int l15 = lane & 15, l4 = lane >> 4;
    const int m0 = blockIdx.y * 128, n0 = blockIdx.x * 128;

    f32x4 acc[4][4];
    const f32x4 zz = {0.f, 0.f, 0.f, 0.f};
#pragma unroll
    for (int i = 0; i < 4; ++i)
#pragma unroll
        for (int j = 0; j < 4; ++j) acc[i][j] = zz;

    const int r0 = tid >> 2, q0q = (tid & 3) * 8;          // chunk tid
    const int r1 = (tid + 256) >> 2, q1q = ((tid + 256) & 3) * 8;

    for (int k0 = 0; k0 < K; k0 += 32) {
        gload16(&A [(size_t)(m0 + r0) * K + k0 + q0q], &As[tid * 8]);
        gload16(&Bt[(size_t)(n0 + r0) * K + k0 + q0q], &Bs[tid * 8]);
        gload16(&A [(size_t)(m0 + r1) * K + k0 + q1q], &As[(tid + 256) * 8]);
        gload16(&Bt[(size_t)(n0 + r1) * K + k0 + q1q], &Bs[(tid + 256) * 8]);
        __syncthreads();
        s16x8 af[4], bw[4];
#pragma unroll
        for (int i = 0; i < 4; ++i)
            af[i] = *(const s16x8*)&As[(wr * 64 + i * 16 + l15) * 32 + l4 * 8];
#pragma unroll
        for (int j = 0; j < 4; ++j)
            bw[j] = *(const s16x8*)&Bs[(wc * 64 + j * 16 + l15) * 32 + l4 * 8];
#pragma unroll
        for (int i = 0; i < 4; ++i)
#pragma unroll
            for (int j = 0; j < 4; ++j)
                acc[i][j] = __builtin_amdgcn_mfma_f32_16x16x32_bf16(
                    __builtin_bit_cast(bf16x8, af[i]),
                    __builtin_bit_cast(bf16x8, bw[j]), acc[i][j], 0, 0, 0);
        __syncthreads();
    }

    // epilogue; C/D layout: col = lane&15, row = (lane>>4)*4 + reg  [HW-verified]
#pragma unroll
    for (int i = 0; i < 4; ++i) {
        const int rb = m0 + wr * 64 + i * 16 + l4 * 4;
#pragma unroll
        for (int j = 0; j < 4; ++j) {
            const int col = n0 + wc * 64 + j * 16 + l15;
            const float bval = (MODE == 0) ? 0.0f : bias[col];
#pragma unroll
            for (int r = 0; r < 4; ++r) {
                const size_t o = (size_t)(rb + r) * N + col;
                const float v = acc[i][j][r];
                if (MODE == 0)      Ob[o] = f2bf(v);
                else if (MODE == 1) RES[o] += v + bval;
                else if (MODE == 2) Ob[o] = f2bf(fmaxf(v + bval, 0.0f));
                else                Of[o] = v + bval;
            }
        }
    }
}

// ---------------- MFMA flash attention, causal. grid (T/64, B*H), 256 thr = 4 waves.
// Wave wq owns q rows [qt*64 + wq*16, +16). KV tiles of 64. HS=64, scale=0.125.
__global__ __launch_bounds__(256) void attn_mfma_k(const u16* __restrict__ Qg,
                                                   const u16* __restrict__ Kg,
                                                   const u16* __restrict__ Vg,
                                                   u16* __restrict__ Og)
{
    const int qt  = blockIdx.x;
    const int bh  = blockIdx.y;
    const int b   = bh >> 4, h = bh & 15;
    const int tid = threadIdx.x;
    const int wq  = tid >> 6, lane = tid & 63;
    const int l15 = lane & 15, l4 = lane >> 4;

    __shared__ __align__(16) u16 Ks[64][72];      // K rows (kv), 144B stride
    __shared__ __align__(16) u16 Vt[64][72];      // V transposed: Vt[d][kv]
    __shared__ __align__(16) u16 Ps[4][16][72];   // per-wave P[qrow][k]

    const int q0 = qt * 64;
    const int qrow0 = q0 + wq * 16;

    // Q fragments (rows qrow0+l15, k = HS dims)
    s16x8 aQ[2];
    {
        const u16* qsrc = Qg + ((size_t)(b * 1024 + qrow0 + l15)) * 1024 + h * 64;
        aQ[0] = *(const s16x8*)(qsrc + l4 * 8);
        aQ[1] = *(const s16x8*)(qsrc + 32 + l4 * 8);
    }

    f32x4 O[4];
    const f32x4 zz = {0.f, 0.f, 0.f, 0.f};
#pragma unroll
    for (int dj = 0; dj < 4; ++dj) O[dj] = zz;
    float mrow[4] = {-3.0e38f, -3.0e38f, -3.0e38f, -3.0e38f};
    float lrow[4] = {0.f, 0.f, 0.f, 0.f};

    // staging assignments
    const int srow = tid >> 3;              // K: row 0..31 (x2), 8 lanes per row
    const int soff = (tid & 7) * 8;
    const int vr   = tid >> 3;              // V: kv row-pair index 0..31
    const int vdg  = tid & 7;               // d-group

    for (int t = 0; t <= qt; ++t) {
        const int kv0 = t * 64;
        __syncthreads();
        // stage K rows [kv0..kv0+64)
        {
            const u16* kb0 = Kg + ((size_t)(b * 1024 + kv0 + srow)) * 1024 + h * 64 + soff;
            *(s16x8*)&Ks[srow][soff]      = *(const s16x8*)kb0;
            *(s16x8*)&Ks[srow + 32][soff] = *(const s16x8*)(kb0 + 32 * 1024);
        }
        // stage V transposed (u32-packed: rows 2vr, 2vr+1)
        {
            const u16* vb0 = Vg + ((size_t)(b * 1024 + kv0 + 2 * vr)) * 1024 + h * 64 + vdg * 8;
            s16x8 v0 = *(const s16x8*)vb0;
            s16x8 v1 = *(const s16x8*)(vb0 + 1024);
#pragma unroll
            for (int e = 0; e < 8; ++e) {
                u32 pk = (u32)(u16)v0[e] | ((u32)(u16)v1[e] << 16);
                *(u32*)&Vt[vdg * 8 + e][2 * vr] = pk;
            }
        }
        __syncthreads();

        // S = (Q K^T) * scale ; S[kc] cols kc*16+l15, rows l4*4+r
        f32x4 S[4];
#pragma unroll
        for (int kc = 0; kc < 4; ++kc) {
            f32x4 s = zz;
            s16x8 bK0 = *(const s16x8*)&Ks[kc * 16 + l15][l4 * 8];
            s16x8 bK1 = *(const s16x8*)&Ks[kc * 16 + l15][32 + l4 * 8];
            s = __builtin_amdgcn_mfma_f32_16x16x32_bf16(
                __builtin_bit_cast(bf16x8, aQ[0]), __builtin_bit_cast(bf16x8, bK0), s, 0, 0, 0);
            s = __builtin_amdgcn_mfma_f32_16x16x32_bf16(
                __builtin_bit_cast(bf16x8, aQ[1]), __builtin_bit_cast(bf16x8, bK1), s, 0, 0, 0);
#pragma unroll
            for (int r = 0; r < 4; ++r) S[kc][r] = s[r] * 0.125f;
        }
        // causal mask on diagonal tile
        if (t == qt) {
#pragma unroll
            for (int kc = 0; kc < 4; ++kc) {
                const int k = kv0 + kc * 16 + l15;
#pragma unroll
                for (int r = 0; r < 4; ++r)
                    if (k > qrow0 + l4 * 4 + r) S[kc][r] = -3.0e38f;
            }
        }
        // online softmax per q-row
        float mloc[4];
#pragma unroll
        for (int r = 0; r < 4; ++r)
            mloc[r] = fmaxf(fmaxf(S[0][r], S[1][r]), fmaxf(S[2][r], S[3][r]));
#pragma unroll
        for (int off = 1; off < 16; off <<= 1)
#pragma unroll
            for (int r = 0; r < 4; ++r) mloc[r] = fmaxf(mloc[r], __shfl_xor(mloc[r], off));
        float alpha[4];
#pragma unroll
        for (int r = 0; r < 4; ++r) {
            const float mnew = fmaxf(mrow[r], mloc[r]);
            alpha[r] = __expf(mrow[r] - mnew);
            mrow[r] = mnew;
        }
        float psum[4] = {0.f, 0.f, 0.f, 0.f};
        f32x4 P[4];
#pragma unroll
        for (int kc = 0; kc < 4; ++kc)
#pragma unroll
            for (int r = 0; r < 4; ++r) {
                const float p = __expf(S[kc][r] - mrow[r]);
                P[kc][r] = p;
                psum[r] += p;
            }
#pragma unroll
        for (int off = 1; off < 16; off <<= 1)
#pragma unroll
            for (int r = 0; r < 4; ++r) psum[r] += __shfl_xor(psum[r], off);
#pragma unroll
        for (int r = 0; r < 4; ++r) lrow[r] = lrow[r] * alpha[r] + psum[r];
#pragma unroll
        for (int dj = 0; dj < 4; ++dj)
#pragma unroll
            for (int r = 0; r < 4; ++r) O[dj][r] *= alpha[r];
        // P -> LDS (bf16) in A-fragment layout source
#pragma unroll
        for (int kc = 0; kc < 4; ++kc)
#pragma unroll
            for (int r = 0; r < 4; ++r)
                Ps[wq][l4 * 4 + r][kc * 16 + l15] = f2bf(P[kc][r]);
        __syncthreads();
        // O += P V  (A = P rows l15, B = Vt rows d)
#pragma unroll
        for (int kk = 0; kk < 2; ++kk) {
            s16x8 aP = *(const s16x8*)&Ps[wq][l15][kk * 32 + l4 * 8];
#pragma unroll
            for (int dj = 0; dj < 4; ++dj) {
                s16x8 bV = *(const s16x8*)&Vt[dj * 16 + l15][kk * 32 + l4 * 8];
                O[dj] = __builtin_amdgcn_mfma_f32_16x16x32_bf16(
                    __builtin_bit_cast(bf16x8, aP), __builtin_bit_cast(bf16x8, bV), O[dj], 0, 0, 0);
            }
        }
    }
    // epilogue: O / l -> bf16
#pragma unroll
    for (int dj = 0; dj < 4; ++dj)
#pragma unroll
        for (int r = 0; r < 4; ++r) {
            const size_t o = ((size_t)(b * 1024 + qrow0 + l4 * 4 + r)) * 1024 + h * 64 + dj * 16 + l15;
            Og[o] = f2bf(O[dj][r] / lrow[r]);
        }
}

// ---------------- orchestration
extern "C" void kernel_launch(void* const* d_in, const int* in_sizes, int n_in,
                              void* d_out, int out_size, void* d_ws, size_t ws_size,
                              hipStream_t stream)
{
    (void)in_sizes; (void)n_in; (void)out_size; (void)ws_size;
    const int*   idx  = (const int*)  d_in[0];
    const float* tok  = (const float*)d_in[1];
    const float* pos  = (const float*)d_in[2];
    const float* Wq   = (const float*)d_in[3];
    const float* Wk   = (const float*)d_in[4];
    const float* Wv   = (const float*)d_in[5];
    const float* Wo   = (const float*)d_in[6];
    const float* bo   = (const float*)d_in[7];
    const float* ln1g = (const float*)d_in[8];
    const float* ln1b = (const float*)d_in[9];
    const float* ln2g = (const float*)d_in[10];
    const float* ln2b = (const float*)d_in[11];
    const float* W1   = (const float*)d_in[12];
    const float* b1   = (const float*)d_in[13];
    const float* W2   = (const float*)d_in[14];
    const float* b2   = (const float*)d_in[15];
    const float* lnfg = (const float*)d_in[16];
    const float* lnfb = (const float*)d_in[17];
    const float* Wh   = (const float*)d_in[18];
    const float* bh   = (const float*)d_in[19];

    char* p = (char*)d_ws;
    float* x = (float*)p;  p += (size_t)8192 * 1024 * 4;
    u16* h   = (u16*)p;    p += (size_t)8192 * 1024 * 2;
    u16* qb  = (u16*)p;    p += (size_t)8192 * 1024 * 2;
    u16* kb  = (u16*)p;    p += (size_t)8192 * 1024 * 2;
    u16* vb  = (u16*)p;    p += (size_t)8192 * 1024 * 2;
    u16* ab  = (u16*)p;    p += (size_t)8192 * 1024 * 2;
    u16* fb  = (u16*)p;    p += (size_t)8192 * 4096 * 2;
    u16* wqT = (u16*)p;    p += (size_t)1024 * 1024 * 2;
    u16* wkT = (u16*)p;    p += (size_t)1024 * 1024 * 2;
    u16* wvT = (u16*)p;    p += (size_t)1024 * 1024 * 2;
    u16* woT = (u16*)p;    p += (size_t)1024 * 1024 * 2;
    u16* w1T = (u16*)p;    p += (size_t)1024 * 4096 * 2;
    u16* w2T = (u16*)p;    p += (size_t)4096 * 1024 * 2;
    u16* whT = (u16*)p;    p += (size_t)1024 * 256 * 2;

    const dim3 tb(32, 8);
    embed_k<<<8192, 256, 0, stream>>>(idx, tok, pos, x);
    for (int l = 0; l < 6; ++l) {
        transpose_k<<<dim3(32, 32),  tb, 0, stream>>>(Wq + (size_t)l * 1048576, wqT, 1024, 1024);
        transpose_k<<<dim3(32, 32),  tb, 0, stream>>>(Wk + (size_t)l * 1048576, wkT, 1024, 1024);
        transpose_k<<<dim3(32, 32),  tb, 0, stream>>>(Wv + (size_t)l * 1048576, wvT, 1024, 1024);
        transpose_k<<<dim3(32, 32),  tb, 0, stream>>>(Wo + (size_t)l * 1048576, woT, 1024, 1024);
        transpose_k<<<dim3(128, 32), tb, 0, stream>>>(W1 + (size_t)l * 4194304, w1T, 1024, 4096);
        transpose_k<<<dim3(32, 128), tb, 0, stream>>>(W2 + (size_t)l * 4194304, w2T, 4096, 1024);

        ln_k<<<8192, 256, 0, stream>>>(x, ln1g + l * 1024, ln1b + l * 1024, h);
        gemm_bt<0><<<dim3(8, 64),  256, 0, stream>>>(h, wqT, nullptr, nullptr, qb, nullptr, 1024, 1024);
        gemm_bt<0><<<dim3(8, 64),  256, 0, stream>>>(h, wkT, nullptr, nullptr, kb, nullptr, 1024, 1024);
        gemm_bt<0><<<dim3(8, 64),  256, 0, stream>>>(h, wvT, nullptr, nullptr, vb, nullptr, 1024, 1024);
        attn_mfma_k<<<dim3(16, 128), 256, 0, stream>>>(qb, kb, vb, ab);
        gemm_bt<1><<<dim3(8, 64),  256, 0, stream>>>(ab, woT, bo + l * 1024, x, nullptr, nullptr, 1024, 1024);
        ln_k<<<8192, 256, 0, stream>>>(x, ln2g + l * 1024, ln2b + l * 1024, h);
        gemm_bt<2><<<dim3(32, 64), 256, 0, stream>>>(h, w1T, b1 + l * 4096, nullptr, fb, nullptr, 4096, 1024);
        gemm_bt<1><<<dim3(8, 64),  256, 0, stream>>>(fb, w2T, b2 + l * 1024, x, nullptr, nullptr, 1024, 4096);
    }
    transpose_k<<<dim3(8, 32), tb, 0, stream>>>(Wh, whT, 1024, 256);
    ln_k<<<8192, 256, 0, stream>>>(x, lnfg, lnfb, h);
    gemm_bt<3><<<dim3(2, 64), 256, 0, stream>>>(h, whT, bh, nullptr, nullptr, (float*)d_out, 256, 1024);
}

// Round 3
// 2949.471 us; speedup vs baseline: 2.6688x; 1.0966x over previous
//
#include <hip/hip_runtime.h>

typedef unsigned short u16;
typedef unsigned int   u32;
typedef __attribute__((ext_vector_type(4))) float  f32x4;
typedef __attribute__((ext_vector_type(8))) __bf16 bf16x8;
typedef __attribute__((ext_vector_type(8))) short  s16x8;
typedef __attribute__((ext_vector_type(4))) unsigned short u16x4;

#define DEVFN __device__ __forceinline__

DEVFN float bf2f(u16 u) {
    u32 v = ((u32)u) << 16;
    return __builtin_bit_cast(float, v);
}
DEVFN u16 f2bf(float f) {   // round-to-nearest-even
    u32 u = __builtin_bit_cast(u32, f);
    u32 r = u + 0x7FFFu + ((u >> 16) & 1u);
    return (u16)(r >> 16);
}

// async global->LDS, 16B per lane. LDS dest must be linear in lane order.
DEVFN void gload16(const void* g, void* l) {
    __builtin_amdgcn_global_load_lds(
        (const __attribute__((address_space(1))) void*)g,
        (__attribute__((address_space(3))) void*)l, 16, 0, 0);
}

// ---------------- embedding
__global__ __launch_bounds__(256) void embed_k(const int* __restrict__ idx,
                                               const float* __restrict__ tok,
                                               const float* __restrict__ pos,
                                               float* __restrict__ x)
{
    int i   = blockIdx.x * 256 + threadIdx.x;
    int row = i >> 8;
    int c   = (i & 255) << 2;
    int t   = row & 1023;
    int tk  = idx[row];
    float4 a = *(const float4*)&tok[(size_t)tk * 1024 + c];
    float4 p = *(const float4*)&pos[(size_t)t * 1024 + c];
    float4 r; r.x = a.x + p.x; r.y = a.y + p.y; r.z = a.z + p.z; r.w = a.w + p.w;
    *(float4*)&x[(size_t)row * 1024 + c] = r;
}

// ---------------- fp32 [K,N] -> bf16 [N,K] transpose (weights)
__global__ __launch_bounds__(256) void transpose_k(const float* __restrict__ W,
                                                   u16* __restrict__ Wt, int K, int N)
{
    __shared__ float tile[32][33];
    int n0 = blockIdx.x * 32, k0 = blockIdx.y * 32;
    int xx = threadIdx.x, ty = threadIdx.y;      // block (32,8)
#pragma unroll
    for (int yy = 0; yy < 4; ++yy) {
        int y = ty + yy * 8;
        tile[y][xx] = W[(size_t)(k0 + y) * N + n0 + xx];
    }
    __syncthreads();
#pragma unroll
    for (int yy = 0; yy < 4; ++yy) {
        int y = ty + yy * 8;
        Wt[(size_t)(n0 + y) * K + k0 + xx] = f2bf(tile[xx][y]);
    }
}

// ---------------- LayerNorm: fp32 in -> bf16 out, C=1024, one block per row
__global__ __launch_bounds__(256) void ln_k(const float* __restrict__ x,
                                            const float* __restrict__ g,
                                            const float* __restrict__ b,
                                            u16* __restrict__ out)
{
    const int row = blockIdx.x, tid = threadIdx.x;
    const float4 v = *(const float4*)&x[(size_t)row * 1024 + tid * 4];
    __shared__ float red[8];
    float s = v.x + v.y + v.z + v.w;
#pragma unroll
    for (int off = 32; off > 0; off >>= 1) s += __shfl_down(s, off);
    const int lane = tid & 63, wv = tid >> 6;
    if (lane == 0) red[wv] = s;
    __syncthreads();
    const float mu = (red[0] + red[1] + red[2] + red[3]) * (1.0f / 1024.0f);
    const float dx = v.x - mu, dy = v.y - mu, dz = v.z - mu, dw = v.w - mu;
    float s2 = dx * dx + dy * dy + dz * dz + dw * dw;
#pragma unroll
    for (int off = 32; off > 0; off >>= 1) s2 += __shfl_down(s2, off);
    if (lane == 0) red[4 + wv] = s2;
    __syncthreads();
    const float var = (red[4] + red[5] + red[6] + red[7]) * (1.0f / 1024.0f);
    const float rs  = rsqrtf(var + 1e-5f);
    const float4 gv = *(const float4*)&g[tid * 4];
    const float4 bv = *(const float4*)&b[tid * 4];
    u16x4 o;
    o.x = f2bf(dx * rs * gv.x + bv.x);
    o.y = f2bf(dy * rs * gv.y + bv.y);
    o.z = f2bf(dz * rs * gv.z + bv.z);
    o.w = f2bf(dw * rs * gv.w + bv.w);
    *(u16x4*)&out[(size_t)row * 1024 + tid * 4] = o;
}

// ---------------- bf16 MFMA GEMM:  C[M,N] = A[M,K] @ Bt[N,K]^T (+epilogue)
// MODE 0: Ob = bf16(acc); 1: RES += acc+bias; 2: Ob = bf16(relu(acc+bias)); 3: Of = acc+bias
// 128x128 tile, BK=32, 256 threads = 4 waves (2x2 of 64x64). global_load_lds staging.
template <int MODE>
__global__ __launch_bounds__(256) void gemm_bt(const u16* __restrict__ A,
                                               const u16* __restrict__ Bt,
                                               const float* __restrict__ bias,
                                               float* __restrict__ RES,
                                               u16* __restrict__ Ob,
                                               float* __restrict__ Of,
                                               int N, int K)
{
    __shared__ __align__(16) u16 As[128 * 32];
    __shared__ __align__(16) u16 Bs[128 * 32];
    const int tid  = threadIdx.x;
    const int lane = tid & 63, wave = tid >> 6;
    const int wr = wave >> 1, wc = wave & 1;
    const int l15 = lane & 15, l4 = lane >> 4;
    const int m0 = blockIdx.y * 128, n0 = blockIdx.x * 128;

    f32x4 acc[4][4];
    const f32x4 zz = {0.f, 0.f, 0.f, 0.f};
#pragma unroll
    for (int i = 0; i < 4; ++i)
#pragma unroll
        for (int j = 0; j < 4; ++j) acc[i][j] = zz;

    const int r0 = tid >> 2, q0q = (tid & 3) * 8;
    const int r1 = (tid + 256) >> 2, q1q = ((tid + 256) & 3) * 8;

    for (int k0 = 0; k0 < K; k0 += 32) {
        gload16(&A [(size_t)(m0 + r0) * K + k0 + q0q], &As[tid * 8]);
        gload16(&Bt[(size_t)(n0 + r0) * K + k0 + q0q], &Bs[tid * 8]);
        gload16(&A [(size_t)(m0 + r1) * K + k0 + q1q], &As[(tid + 256) * 8]);
        gload16(&Bt[(size_t)(n0 + r1) * K + k0 + q1q], &Bs[(tid + 256) * 8]);
        __syncthreads();
        s16x8 af[4], bw[4];
#pragma unroll
        for (int i = 0; i < 4; ++i)
            af[i] = *(const s16x8*)&As[(wr * 64 + i * 16 + l15) * 32 + l4 * 8];
#pragma unroll
        for (int j = 0; j < 4; ++j)
            bw[j] = *(const s16x8*)&Bs[(wc * 64 + j * 16 + l15) * 32 + l4 * 8];
#pragma unroll
        for (int i = 0; i < 4; ++i)
#pragma unroll
            for (int j = 0; j < 4; ++j)
                acc[i][j] = __builtin_amdgcn_mfma_f32_16x16x32_bf16(
                    __builtin_bit_cast(bf16x8, af[i]),
                    __builtin_bit_cast(bf16x8, bw[j]), acc[i][j], 0, 0, 0);
        __syncthreads();
    }

    // epilogue; C/D layout: col = lane&15, row = (lane>>4)*4 + reg
#pragma unroll
    for (int i = 0; i < 4; ++i) {
        const int rb = m0 + wr * 64 + i * 16 + l4 * 4;
#pragma unroll
        for (int j = 0; j < 4; ++j) {
            const int col = n0 + wc * 64 + j * 16 + l15;
            const float bval = (MODE == 0) ? 0.0f : bias[col];
#pragma unroll
            for (int r = 0; r < 4; ++r) {
                const size_t o = (size_t)(rb + r) * N + col;
                const float v = acc[i][j][r];
                if (MODE == 0)      Ob[o] = f2bf(v);
                else if (MODE == 1) RES[o] += v + bval;
                else if (MODE == 2) Ob[o] = f2bf(fmaxf(v + bval, 0.0f));
                else                Of[o] = v + bval;
            }
        }
    }
}

// ---------------- MFMA flash attention v2, causal.
// grid (T/128, B*H) with qt reversed; 256 thr = 4 waves; wave owns 32 q rows
// (2x 16-row frags). KV tiles of 64. Q/K/V read from fused qkv buffer (stride 3072).
__global__ __launch_bounds__(256) void attn_mfma_k(const u16* __restrict__ QKV,
                                                   u16* __restrict__ Og)
{
    const int qt  = (int)(gridDim.x - 1 - blockIdx.x);   // heavy blocks first
    const int bh  = blockIdx.y;
    const int b   = bh >> 4, h = bh & 15;
    const int tid = threadIdx.x;
    const int wq  = tid >> 6, lane = tid & 63;
    const int l15 = lane & 15, l4 = lane >> 4;

    __shared__ __align__(16) u16 Ks[64][72];     // K rows, 144B stride
    __shared__ __align__(16) u16 Vt[64][72];     // V^T rows d; u32 kv-pairs, rotated cols
    __shared__ __align__(16) u16 Ps[4][16][68];  // per-wave P (reused per qi)
    u32* VtW = (u32*)&Vt[0][0];                  // row stride 36 u32

    const int qrow0 = qt * 128 + wq * 32;

    const u16* Qbase = QKV + (size_t)b * 1024 * 3072 + h * 64;
    const u16* Kbase = Qbase + 1024;
    const u16* Vbase = Qbase + 2048;

    // Q fragments: rows qrow0 + qi*16 + l15, k halves
    s16x8 aQ[2][2];
#pragma unroll
    for (int qi = 0; qi < 2; ++qi) {
        const u16* qsrc = Qbase + (size_t)(qrow0 + qi * 16 + l15) * 3072;
        aQ[qi][0] = *(const s16x8*)(qsrc + l4 * 8);
        aQ[qi][1] = *(const s16x8*)(qsrc + 32 + l4 * 8);
    }

    f32x4 O[2][4];
    const f32x4 zz = {0.f, 0.f, 0.f, 0.f};
    float mrow[2][4], lrow[2][4];
#pragma unroll
    for (int qi = 0; qi < 2; ++qi) {
#pragma unroll
        for (int dj = 0; dj < 4; ++dj) O[qi][dj] = zz;
#pragma unroll
        for (int r = 0; r < 4; ++r) { mrow[qi][r] = -3.0e38f; lrow[qi][r] = 0.f; }
    }

    const int srow = tid >> 3;              // K staging: rows 0..31 (+32)
    const int soff = (tid & 7) * 8;
    const int vp   = tid >> 3;              // V staging: kv-pair 0..31
    const int vdg  = tid & 7;               // d-group 0..7

    const int ntiles = 2 * qt + 2;
    for (int t = 0; t < ntiles; ++t) {
        const int kv0 = t * 64;
        __syncthreads();   // all waves done reading Ks/Vt of prev tile
        {
            const u16* kb0 = Kbase + (size_t)(kv0 + srow) * 3072 + soff;
            *(s16x8*)&Ks[srow][soff]      = *(const s16x8*)kb0;
            *(s16x8*)&Ks[srow + 32][soff] = *(const s16x8*)(kb0 + (size_t)32 * 3072);
        }
        {
            const u16* vb0 = Vbase + (size_t)(kv0 + 2 * vp) * 3072 + vdg * 8;
            s16x8 v0 = *(const s16x8*)vb0;
            s16x8 v1 = *(const s16x8*)(vb0 + 3072);
#pragma unroll
            for (int e = 0; e < 8; ++e) {
                const int d = vdg * 8 + e;
                const int c = (vp + 4 * vdg) & 31;   // rotated col
                u32 pk = (u32)(u16)v0[e] | ((u32)(u16)v1[e] << 16);
                VtW[d * 36 + c] = pk;
            }
        }
        __syncthreads();   // staging visible

#pragma unroll
        for (int qi = 0; qi < 2; ++qi) {
            const int qlo = qrow0 + qi * 16;
            if (kv0 > qlo + 15) continue;            // fully masked frag
            // S = QK^T * scale
            f32x4 S[4];
#pragma unroll
            for (int kc = 0; kc < 4; ++kc) {
                f32x4 s = zz;
                s16x8 bK0 = *(const s16x8*)&Ks[kc * 16 + l15][l4 * 8];
                s16x8 bK1 = *(const s16x8*)&Ks[kc * 16 + l15][32 + l4 * 8];
                s = __builtin_amdgcn_mfma_f32_16x16x32_bf16(
                    __builtin_bit_cast(bf16x8, aQ[qi][0]), __builtin_bit_cast(bf16x8, bK0), s, 0, 0, 0);
                s = __builtin_amdgcn_mfma_f32_16x16x32_bf16(
                    __builtin_bit_cast(bf16x8, aQ[qi][1]), __builtin_bit_cast(bf16x8, bK1), s, 0, 0, 0);
#pragma unroll
                for (int r = 0; r < 4; ++r) S[kc][r] = s[r] * 0.125f;
            }
            if (kv0 + 63 > qlo) {                     // diagonal: elementwise mask
#pragma unroll
                for (int kc = 0; kc < 4; ++kc) {
                    const int k = kv0 + kc * 16 + l15;
#pragma unroll
                    for (int r = 0; r < 4; ++r)
                        if (k > qlo + l4 * 4 + r) S[kc][r] = -3.0e38f;
                }
            }
            // online softmax
            float mloc[4];
#pragma unroll
            for (int r = 0; r < 4; ++r)
                mloc[r] = fmaxf(fmaxf(S[0][r], S[1][r]), fmaxf(S[2][r], S[3][r]));
#pragma unroll
            for (int off = 1; off < 16; off <<= 1)
#pragma unroll
                for (int r = 0; r < 4; ++r) mloc[r] = fmaxf(mloc[r], __shfl_xor(mloc[r], off));
            float alpha[4];
#pragma unroll
            for (int r = 0; r < 4; ++r) {
                const float mnew = fmaxf(mrow[qi][r], mloc[r]);
                alpha[r] = __expf(mrow[qi][r] - mnew);
                mrow[qi][r] = mnew;
            }
            float psum[4] = {0.f, 0.f, 0.f, 0.f};
#pragma unroll
            for (int kc = 0; kc < 4; ++kc)
#pragma unroll
                for (int r = 0; r < 4; ++r) {
                    const float p = __expf(S[kc][r] - mrow[qi][r]);
                    Ps[wq][l4 * 4 + r][kc * 16 + l15] = f2bf(p);
                    psum[r] += p;
                }
#pragma unroll
            for (int off = 1; off < 16; off <<= 1)
#pragma unroll
                for (int r = 0; r < 4; ++r) psum[r] += __shfl_xor(psum[r], off);
#pragma unroll
            for (int r = 0; r < 4; ++r) lrow[qi][r] = lrow[qi][r] * alpha[r] + psum[r];
#pragma unroll
            for (int dj = 0; dj < 4; ++dj)
#pragma unroll
                for (int r = 0; r < 4; ++r) O[qi][dj][r] *= alpha[r];
            // PV (Ps is wave-private: compiler's lgkmcnt handles write->read)
#pragma unroll
            for (int kk = 0; kk < 2; ++kk) {
                s16x8 aP = *(const s16x8*)&Ps[wq][l15][kk * 32 + l4 * 8];
#pragma unroll
                for (int dj = 0; dj < 4; ++dj) {
                    const int d = dj * 16 + l15;
                    const int c = (kk * 16 + l4 * 4 + 4 * ((d >> 3) & 7)) & 31;
                    s16x8 bV = *(const s16x8*)&VtW[d * 36 + c];
                    O[qi][dj] = __builtin_amdgcn_mfma_f32_16x16x32_bf16(
                        __builtin_bit_cast(bf16x8, aP), __builtin_bit_cast(bf16x8, bV),
                        O[qi][dj], 0, 0, 0);
                }
            }
        }
    }
    // epilogue
#pragma unroll
    for (int qi = 0; qi < 2; ++qi)
#pragma unroll
        for (int dj = 0; dj < 4; ++dj)
#pragma unroll
            for (int r = 0; r < 4; ++r) {
                const size_t o = ((size_t)(b * 1024 + qrow0 + qi * 16 + l4 * 4 + r)) * 1024
                               + h * 64 + dj * 16 + l15;
                Og[o] = f2bf(O[qi][dj][r] / lrow[qi][r]);
            }
}

// ---------------- orchestration
extern "C" void kernel_launch(void* const* d_in, const int* in_sizes, int n_in,
                              void* d_out, int out_size, void* d_ws, size_t ws_size,
                              hipStream_t stream)
{
    (void)in_sizes; (void)n_in; (void)out_size; (void)ws_size;
    const int*   idx  = (const int*)  d_in[0];
    const float* tok  = (const float*)d_in[1];
    const float* pos  = (const float*)d_in[2];
    const float* Wq   = (const float*)d_in[3];
    const float* Wk   = (const float*)d_in[4];
    const float* Wv   = (const float*)d_in[5];
    const float* Wo   = (const float*)d_in[6];
    const float* bo   = (const float*)d_in[7];
    const float* ln1g = (const float*)d_in[8];
    const float* ln1b = (const float*)d_in[9];
    const float* ln2g = (const float*)d_in[10];
    const float* ln2b = (const float*)d_in[11];
    const float* W1   = (const float*)d_in[12];
    const float* b1   = (const float*)d_in[13];
    const float* W2   = (const float*)d_in[14];
    const float* b2   = (const float*)d_in[15];
    const float* lnfg = (const float*)d_in[16];
    const float* lnfb = (const float*)d_in[17];
    const float* Wh   = (const float*)d_in[18];
    const float* bh   = (const float*)d_in[19];

    char* p = (char*)d_ws;
    float* x  = (float*)p; p += (size_t)8192 * 1024 * 4;
    u16* h    = (u16*)p;   p += (size_t)8192 * 1024 * 2;
    u16* qkv  = (u16*)p;   p += (size_t)8192 * 3072 * 2;
    u16* ab   = (u16*)p;   p += (size_t)8192 * 1024 * 2;
    u16* fb   = (u16*)p;   p += (size_t)8192 * 4096 * 2;
    u16* wqT  = (u16*)p;   p += (size_t)1024 * 1024 * 2;   // wq/wk/wv contiguous -> [3072][1024]
    u16* wkT  = (u16*)p;   p += (size_t)1024 * 1024 * 2;
    u16* wvT  = (u16*)p;   p += (size_t)1024 * 1024 * 2;
    u16* woT  = (u16*)p;   p += (size_t)1024 * 1024 * 2;
    u16* w1T  = (u16*)p;   p += (size_t)1024 * 4096 * 2;
    u16* w2T  = (u16*)p;   p += (size_t)4096 * 1024 * 2;
    u16* whT  = (u16*)p;   p += (size_t)1024 * 256 * 2;

    const dim3 tb(32, 8);
    embed_k<<<8192, 256, 0, stream>>>(idx, tok, pos, x);
    for (int l = 0; l < 6; ++l) {
        transpose_k<<<dim3(32, 32),  tb, 0, stream>>>(Wq + (size_t)l * 1048576, wqT, 1024, 1024);
        transpose_k<<<dim3(32, 32),  tb, 0, stream>>>(Wk + (size_t)l * 1048576, wkT, 1024, 1024);
        transpose_k<<<dim3(32, 32),  tb, 0, stream>>>(Wv + (size_t)l * 1048576, wvT, 1024, 1024);
        transpose_k<<<dim3(32, 32),  tb, 0, stream>>>(Wo + (size_t)l * 1048576, woT, 1024, 1024);
        transpose_k<<<dim3(128, 32), tb, 0, stream>>>(W1 + (size_t)l * 4194304, w1T, 1024, 4096);
        transpose_k<<<dim3(32, 128), tb, 0, stream>>>(W2 + (size_t)l * 4194304, w2T, 4096, 1024);

        ln_k<<<8192, 256, 0, stream>>>(x, ln1g + l * 1024, ln1b + l * 1024, h);
        gemm_bt<0><<<dim3(24, 64), 256, 0, stream>>>(h, wqT, nullptr, nullptr, qkv, nullptr, 3072, 1024);
        attn_mfma_k<<<dim3(8, 128), 256, 0, stream>>>(qkv, ab);
        gemm_bt<1><<<dim3(8, 64),  256, 0, stream>>>(ab, woT, bo + l * 1024, x, nullptr, nullptr, 1024, 1024);
        ln_k<<<8192, 256, 0, stream>>>(x, ln2g + l * 1024, ln2b + l * 1024, h);
        gemm_bt<2><<<dim3(32, 64), 256, 0, stream>>>(h, w1T, b1 + l * 4096, nullptr, fb, nullptr, 4096, 1024);
        gemm_bt<1><<<dim3(8, 64),  256, 0, stream>>>(fb, w2T, b2 + l * 1024, x, nullptr, nullptr, 1024, 4096);
    }
    transpose_k<<<dim3(8, 32), tb, 0, stream>>>(Wh, whT, 1024, 256);
    ln_k<<<8192, 256, 0, stream>>>(x, lnfg, lnfb, h);
    gemm_bt<3><<<dim3(2, 64), 256, 0, stream>>>(h, whT, bh, nullptr, nullptr, (float*)d_out, 256, 1024);
}

// Round 4
// 2777.152 us; speedup vs baseline: 2.8344x; 1.0620x over previous
//
#include <hip/hip_runtime.h>

typedef unsigned short u16;
typedef unsigned int   u32;
typedef __attribute__((ext_vector_type(4))) float  f32x4;
typedef __attribute__((ext_vector_type(8))) __bf16 bf16x8;
typedef __attribute__((ext_vector_type(8))) short  s16x8;
typedef __attribute__((ext_vector_type(4))) unsigned short u16x4;

#define DEVFN __device__ __forceinline__

DEVFN float bf2f(u16 u) {
    u32 v = ((u32)u) << 16;
    return __builtin_bit_cast(float, v);
}
DEVFN u16 f2bf(float f) {   // round-to-nearest-even
    u32 u = __builtin_bit_cast(u32, f);
    u32 r = u + 0x7FFFu + ((u >> 16) & 1u);
    return (u16)(r >> 16);
}

// async global->LDS, 16B per lane. LDS dest must be linear in lane order.
DEVFN void gload16(const void* g, void* l) {
    __builtin_amdgcn_global_load_lds(
        (const __attribute__((address_space(1))) void*)g,
        (__attribute__((address_space(3))) void*)l, 16, 0, 0);
}

// ---------------- embedding
__global__ __launch_bounds__(256) void embed_k(const int* __restrict__ idx,
                                               const float* __restrict__ tok,
                                               const float* __restrict__ pos,
                                               float* __restrict__ x)
{
    int i   = blockIdx.x * 256 + threadIdx.x;
    int row = i >> 8;
    int c   = (i & 255) << 2;
    int t   = row & 1023;
    int tk  = idx[row];
    float4 a = *(const float4*)&tok[(size_t)tk * 1024 + c];
    float4 p = *(const float4*)&pos[(size_t)t * 1024 + c];
    float4 r; r.x = a.x + p.x; r.y = a.y + p.y; r.z = a.z + p.z; r.w = a.w + p.w;
    *(float4*)&x[(size_t)row * 1024 + c] = r;
}

// ---------------- fp32 [K,N] -> bf16 [N,K] transpose (weights)
__global__ __launch_bounds__(256) void transpose_k(const float* __restrict__ W,
                                                   u16* __restrict__ Wt, int K, int N)
{
    __shared__ float tile[32][33];
    int n0 = blockIdx.x * 32, k0 = blockIdx.y * 32;
    int xx = threadIdx.x, ty = threadIdx.y;      // block (32,8)
#pragma unroll
    for (int yy = 0; yy < 4; ++yy) {
        int y = ty + yy * 8;
        tile[y][xx] = W[(size_t)(k0 + y) * N + n0 + xx];
    }
    __syncthreads();
#pragma unroll
    for (int yy = 0; yy < 4; ++yy) {
        int y = ty + yy * 8;
        Wt[(size_t)(n0 + y) * K + k0 + xx] = f2bf(tile[xx][y]);
    }
}

// ---------------- LayerNorm: fp32 in -> bf16 out, C=1024, one block per row
__global__ __launch_bounds__(256) void ln_k(const float* __restrict__ x,
                                            const float* __restrict__ g,
                                            const float* __restrict__ b,
                                            u16* __restrict__ out)
{
    const int row = blockIdx.x, tid = threadIdx.x;
    const float4 v = *(const float4*)&x[(size_t)row * 1024 + tid * 4];
    __shared__ float red[8];
    float s = v.x + v.y + v.z + v.w;
#pragma unroll
    for (int off = 32; off > 0; off >>= 1) s += __shfl_down(s, off);
    const int lane = tid & 63, wv = tid >> 6;
    if (lane == 0) red[wv] = s;
    __syncthreads();
    const float mu = (red[0] + red[1] + red[2] + red[3]) * (1.0f / 1024.0f);
    const float dx = v.x - mu, dy = v.y - mu, dz = v.z - mu, dw = v.w - mu;
    float s2 = dx * dx + dy * dy + dz * dz + dw * dw;
#pragma unroll
    for (int off = 32; off > 0; off >>= 1) s2 += __shfl_down(s2, off);
    if (lane == 0) red[4 + wv] = s2;
    __syncthreads();
    const float var = (red[4] + red[5] + red[6] + red[7]) * (1.0f / 1024.0f);
    const float rs  = rsqrtf(var + 1e-5f);
    const float4 gv = *(const float4*)&g[tid * 4];
    const float4 bv = *(const float4*)&b[tid * 4];
    u16x4 o;
    o.x = f2bf(dx * rs * gv.x + bv.x);
    o.y = f2bf(dy * rs * gv.y + bv.y);
    o.z = f2bf(dz * rs * gv.z + bv.z);
    o.w = f2bf(dw * rs * gv.w + bv.w);
    *(u16x4*)&out[(size_t)row * 1024 + tid * 4] = o;
}

// ---------------- bf16 MFMA GEMM:  C[M,N] = A[M,K] @ Bt[N,K]^T (+epilogue)
// MODE 0: Ob = bf16(acc); 1: RES += acc+bias; 2: Ob = bf16(relu(acc+bias)); 3: Of = acc+bias
// 128x128 tile, BK=32, 4 waves. 1D grid (nwg%8==0), XCD-bijective swizzle.
// Double-buffered global_load_lds: one barrier per K-step, loads overlap MFMA.
template <int MODE>
__global__ __launch_bounds__(256) void gemm_bt(const u16* __restrict__ A,
                                               const u16* __restrict__ Bt,
                                               const float* __restrict__ bias,
                                               float* __restrict__ RES,
                                               u16* __restrict__ Ob,
                                               float* __restrict__ Of,
                                               int N, int K, int ntx)
{
    __shared__ __align__(16) u16 As[2][128 * 32];
    __shared__ __align__(16) u16 Bs[2][128 * 32];
    const int tid  = threadIdx.x;
    const int lane = tid & 63, wave = tid >> 6;
    const int wr = wave >> 1, wc = wave & 1;
    const int l15 = lane & 15, l4 = lane >> 4;

    // XCD-bijective swizzle: contiguous chunk of blocks per XCD (nwg % 8 == 0)
    const int nwg = (int)gridDim.x;
    const int bid = (int)blockIdx.x;
    const int swz = (bid & 7) * (nwg >> 3) + (bid >> 3);
    const int n0 = (swz % ntx) * 128, m0 = (swz / ntx) * 128;

    f32x4 acc[4][4];
    const f32x4 zz = {0.f, 0.f, 0.f, 0.f};
#pragma unroll
    for (int i = 0; i < 4; ++i)
#pragma unroll
        for (int j = 0; j < 4; ++j) acc[i][j] = zz;

    const int r0 = tid >> 2, q0q = (tid & 3) * 8;
    const int r1 = (tid + 256) >> 2, q1q = ((tid + 256) & 3) * 8;
    const u16* Arow0 = &A [(size_t)(m0 + r0) * K + q0q];
    const u16* Brow0 = &Bt[(size_t)(n0 + r0) * K + q0q];
    const u16* Arow1 = &A [(size_t)(m0 + r1) * K + q1q];
    const u16* Brow1 = &Bt[(size_t)(n0 + r1) * K + q1q];

    // prologue: stage k0=0 into buf 0
    gload16(Arow0, &As[0][tid * 8]);
    gload16(Brow0, &Bs[0][tid * 8]);
    gload16(Arow1, &As[0][(tid + 256) * 8]);
    gload16(Brow1, &Bs[0][(tid + 256) * 8]);
    __syncthreads();

    const int S = K >> 5;
    int cur = 0;
    for (int s = 0; s < S; ++s) {
        if (s + 1 < S) {   // issue next-tile loads; they overlap this tile's MFMA
            const int kn = (s + 1) << 5;
            gload16(Arow0 + kn, &As[cur ^ 1][tid * 8]);
            gload16(Brow0 + kn, &Bs[cur ^ 1][tid * 8]);
            gload16(Arow1 + kn, &As[cur ^ 1][(tid + 256) * 8]);
            gload16(Brow1 + kn, &Bs[cur ^ 1][(tid + 256) * 8]);
        }
        s16x8 af[4], bw[4];
#pragma unroll
        for (int i = 0; i < 4; ++i)
            af[i] = *(const s16x8*)&As[cur][(wr * 64 + i * 16 + l15) * 32 + l4 * 8];
#pragma unroll
        for (int j = 0; j < 4; ++j)
            bw[j] = *(const s16x8*)&Bs[cur][(wc * 64 + j * 16 + l15) * 32 + l4 * 8];
#pragma unroll
        for (int i = 0; i < 4; ++i)
#pragma unroll
            for (int j = 0; j < 4; ++j)
                acc[i][j] = __builtin_amdgcn_mfma_f32_16x16x32_bf16(
                    __builtin_bit_cast(bf16x8, af[i]),
                    __builtin_bit_cast(bf16x8, bw[j]), acc[i][j], 0, 0, 0);
        __syncthreads();   // drains next-tile loads (flew under MFMA) + syncs buffers
        cur ^= 1;
    }

    // epilogue; C/D layout: col = lane&15, row = (lane>>4)*4 + reg
#pragma unroll
    for (int i = 0; i < 4; ++i) {
        const int rb = m0 + wr * 64 + i * 16 + l4 * 4;
#pragma unroll
        for (int j = 0; j < 4; ++j) {
            const int col = n0 + wc * 64 + j * 16 + l15;
            const float bval = (MODE == 0) ? 0.0f : bias[col];
#pragma unroll
            for (int r = 0; r < 4; ++r) {
                const size_t o = (size_t)(rb + r) * N + col;
                const float v = acc[i][j][r];
                if (MODE == 0)      Ob[o] = f2bf(v);
                else if (MODE == 1) RES[o] += v + bval;
                else if (MODE == 2) Ob[o] = f2bf(fmaxf(v + bval, 0.0f));
                else                Of[o] = v + bval;
            }
        }
    }
}

// ---------------- MFMA flash attention v3, causal.
// grid (T/128, B*H) qt reversed; 4 waves; wave owns 32 q rows (2x16 frags).
// KV tiles of 64, double-buffered; async-stage split (issue early / write late);
// one barrier per tile. QKV fused buffer (stride 3072).
__global__ __launch_bounds__(256) void attn_mfma_k(const u16* __restrict__ QKV,
                                                   u16* __restrict__ Og)
{
    const int qt  = (int)(gridDim.x - 1 - blockIdx.x);   // heavy blocks first
    const int bh  = blockIdx.y;
    const int b   = bh >> 4, h = bh & 15;
    const int tid = threadIdx.x;
    const int wq  = tid >> 6, lane = tid & 63;
    const int l15 = lane & 15, l4 = lane >> 4;

    __shared__ __align__(16) u16 Ks[2][64][72];   // K rows, 144B stride
    __shared__ __align__(16) u16 Vt[2][64][72];   // V^T rows d; u32 kv-pairs, rotated cols
    __shared__ __align__(16) u16 Ps[4][16][68];   // per-wave P

    const int qrow0 = qt * 128 + wq * 32;

    const u16* Qbase = QKV + (size_t)b * 1024 * 3072 + h * 64;
    const u16* Kbase = Qbase + 1024;
    const u16* Vbase = Qbase + 2048;

    s16x8 aQ[2][2];
#pragma unroll
    for (int qi = 0; qi < 2; ++qi) {
        const u16* qsrc = Qbase + (size_t)(qrow0 + qi * 16 + l15) * 3072;
        aQ[qi][0] = *(const s16x8*)(qsrc + l4 * 8);
        aQ[qi][1] = *(const s16x8*)(qsrc + 32 + l4 * 8);
    }

    f32x4 O[2][4];
    const f32x4 zz = {0.f, 0.f, 0.f, 0.f};
    float mrow[2][4], lrow[2][4];
#pragma unroll
    for (int qi = 0; qi < 2; ++qi) {
#pragma unroll
        for (int dj = 0; dj < 4; ++dj) O[qi][dj] = zz;
#pragma unroll
        for (int r = 0; r < 4; ++r) { mrow[qi][r] = -3.0e38f; lrow[qi][r] = 0.f; }
    }

    const int srow = tid >> 3;              // K staging: rows 0..31 (+32)
    const int soff = (tid & 7) * 8;
    const int vp   = tid >> 3;              // V staging: kv-pair 0..31
    const int vdg  = tid & 7;               // d-group 0..7
    const int vc   = (vp + 4 * vdg) & 31;   // rotated col for Vt writes

    const int ntiles = 2 * qt + 2;
    s16x8 kr0, kr1, vr0, vr1;

    // prologue: load + write tile 0
    {
        const u16* kb0 = Kbase + (size_t)srow * 3072 + soff;
        kr0 = *(const s16x8*)kb0;
        kr1 = *(const s16x8*)(kb0 + (size_t)32 * 3072);
        const u16* vb0 = Vbase + (size_t)(2 * vp) * 3072 + vdg * 8;
        vr0 = *(const s16x8*)vb0;
        vr1 = *(const s16x8*)(vb0 + 3072);
        *(s16x8*)&Ks[0][srow][soff]      = kr0;
        *(s16x8*)&Ks[0][srow + 32][soff] = kr1;
        u32* VtW = (u32*)&Vt[0][0][0];
#pragma unroll
        for (int e = 0; e < 8; ++e) {
            u32 pk = (u32)(u16)vr0[e] | ((u32)(u16)vr1[e] << 16);
            VtW[(vdg * 8 + e) * 36 + vc] = pk;
        }
    }
    __syncthreads();

    int cur = 0;
    for (int t = 0; t < ntiles; ++t) {
        const int kv0 = t * 64;
        const bool more = (t + 1 < ntiles);
        if (more) {   // issue next-tile global loads; land during compute
            const u16* kb0 = Kbase + (size_t)(kv0 + 64 + srow) * 3072 + soff;
            kr0 = *(const s16x8*)kb0;
            kr1 = *(const s16x8*)(kb0 + (size_t)32 * 3072);
            const u16* vb0 = Vbase + (size_t)(kv0 + 64 + 2 * vp) * 3072 + vdg * 8;
            vr0 = *(const s16x8*)vb0;
            vr1 = *(const s16x8*)(vb0 + 3072);
        }
        const u32* VtW = (const u32*)&Vt[cur][0][0];

#pragma unroll
        for (int qi = 0; qi < 2; ++qi) {
            const int qlo = qrow0 + qi * 16;
            if (kv0 > qlo + 15) continue;            // fully masked frag
            f32x4 S[4];
            __builtin_amdgcn_s_setprio(1);
#pragma unroll
            for (int kc = 0; kc < 4; ++kc) {
                f32x4 s = zz;
                s16x8 bK0 = *(const s16x8*)&Ks[cur][kc * 16 + l15][l4 * 8];
                s16x8 bK1 = *(const s16x8*)&Ks[cur][kc * 16 + l15][32 + l4 * 8];
                s = __builtin_amdgcn_mfma_f32_16x16x32_bf16(
                    __builtin_bit_cast(bf16x8, aQ[qi][0]), __builtin_bit_cast(bf16x8, bK0), s, 0, 0, 0);
                s = __builtin_amdgcn_mfma_f32_16x16x32_bf16(
                    __builtin_bit_cast(bf16x8, aQ[qi][1]), __builtin_bit_cast(bf16x8, bK1), s, 0, 0, 0);
#pragma unroll
                for (int r = 0; r < 4; ++r) S[kc][r] = s[r] * 0.125f;
            }
            __builtin_amdgcn_s_setprio(0);
            if (kv0 + 63 > qlo) {                     // diagonal: elementwise mask
#pragma unroll
                for (int kc = 0; kc < 4; ++kc) {
                    const int k = kv0 + kc * 16 + l15;
#pragma unroll
                    for (int r = 0; r < 4; ++r)
                        if (k > qlo + l4 * 4 + r) S[kc][r] = -3.0e38f;
                }
            }
            float mloc[4];
#pragma unroll
            for (int r = 0; r < 4; ++r)
                mloc[r] = fmaxf(fmaxf(S[0][r], S[1][r]), fmaxf(S[2][r], S[3][r]));
#pragma unroll
            for (int off = 1; off < 16; off <<= 1)
#pragma unroll
                for (int r = 0; r < 4; ++r) mloc[r] = fmaxf(mloc[r], __shfl_xor(mloc[r], off));
            float alpha[4];
#pragma unroll
            for (int r = 0; r < 4; ++r) {
                const float mnew = fmaxf(mrow[qi][r], mloc[r]);
                alpha[r] = __expf(mrow[qi][r] - mnew);
                mrow[qi][r] = mnew;
            }
            float psum[4] = {0.f, 0.f, 0.f, 0.f};
#pragma unroll
            for (int kc = 0; kc < 4; ++kc)
#pragma unroll
                for (int r = 0; r < 4; ++r) {
                    const float p = __expf(S[kc][r] - mrow[qi][r]);
                    Ps[wq][l4 * 4 + r][kc * 16 + l15] = f2bf(p);
                    psum[r] += p;
                }
#pragma unroll
            for (int off = 1; off < 16; off <<= 1)
#pragma unroll
                for (int r = 0; r < 4; ++r) psum[r] += __shfl_xor(psum[r], off);
#pragma unroll
            for (int r = 0; r < 4; ++r) lrow[qi][r] = lrow[qi][r] * alpha[r] + psum[r];
#pragma unroll
            for (int dj = 0; dj < 4; ++dj)
#pragma unroll
                for (int r = 0; r < 4; ++r) O[qi][dj][r] *= alpha[r];
            __builtin_amdgcn_s_setprio(1);
#pragma unroll
            for (int kk = 0; kk < 2; ++kk) {
                s16x8 aP = *(const s16x8*)&Ps[wq][l15][kk * 32 + l4 * 8];
#pragma unroll
                for (int dj = 0; dj < 4; ++dj) {
                    const int d = dj * 16 + l15;
                    const int c = (kk * 16 + l4 * 4 + 4 * ((d >> 3) & 7)) & 31;
                    s16x8 bV = *(const s16x8*)&VtW[d * 36 + c];
                    O[qi][dj] = __builtin_amdgcn_mfma_f32_16x16x32_bf16(
                        __builtin_bit_cast(bf16x8, aP), __builtin_bit_cast(bf16x8, bV),
                        O[qi][dj], 0, 0, 0);
                }
            }
            __builtin_amdgcn_s_setprio(0);
        }

        if (more) {   // write-late: staged regs -> other buffer
            *(s16x8*)&Ks[cur ^ 1][srow][soff]      = kr0;
            *(s16x8*)&Ks[cur ^ 1][srow + 32][soff] = kr1;
            u32* VtWn = (u32*)&Vt[cur ^ 1][0][0];
#pragma unroll
            for (int e = 0; e < 8; ++e) {
                u32 pk = (u32)(u16)vr0[e] | ((u32)(u16)vr1[e] << 16);
                VtWn[(vdg * 8 + e) * 36 + vc] = pk;
            }
        }
        __syncthreads();
        cur ^= 1;
    }
    // epilogue
#pragma unroll
    for (int qi = 0; qi < 2; ++qi)
#pragma unroll
        for (int dj = 0; dj < 4; ++dj)
#pragma unroll
            for (int r = 0; r < 4; ++r) {
                const size_t o = ((size_t)(b * 1024 + qrow0 + qi * 16 + l4 * 4 + r)) * 1024
                               + h * 64 + dj * 16 + l15;
                Og[o] = f2bf(O[qi][dj][r] / lrow[qi][r]);
            }
}

// ---------------- orchestration
extern "C" void kernel_launch(void* const* d_in, const int* in_sizes, int n_in,
                              void* d_out, int out_size, void* d_ws, size_t ws_size,
                              hipStream_t stream)
{
    (void)in_sizes; (void)n_in; (void)out_size; (void)ws_size;
    const int*   idx  = (const int*)  d_in[0];
    const float* tok  = (const float*)d_in[1];
    const float* pos  = (const float*)d_in[2];
    const float* Wq   = (const float*)d_in[3];
    const float* Wk   = (const float*)d_in[4];
    const float* Wv   = (const float*)d_in[5];
    const float* Wo   = (const float*)d_in[6];
    const float* bo   = (const float*)d_in[7];
    const float* ln1g = (const float*)d_in[8];
    const float* ln1b = (const float*)d_in[9];
    const float* ln2g = (const float*)d_in[10];
    const float* ln2b = (const float*)d_in[11];
    const float* W1   = (const float*)d_in[12];
    const float* b1   = (const float*)d_in[13];
    const float* W2   = (const float*)d_in[14];
    const float* b2   = (const float*)d_in[15];
    const float* lnfg = (const float*)d_in[16];
    const float* lnfb = (const float*)d_in[17];
    const float* Wh   = (const float*)d_in[18];
    const float* bh   = (const float*)d_in[19];

    char* p = (char*)d_ws;
    float* x  = (float*)p; p += (size_t)8192 * 1024 * 4;
    u16* h    = (u16*)p;   p += (size_t)8192 * 1024 * 2;
    u16* qkv  = (u16*)p;   p += (size_t)8192 * 3072 * 2;
    u16* ab   = (u16*)p;   p += (size_t)8192 * 1024 * 2;
    u16* fb   = (u16*)p;   p += (size_t)8192 * 4096 * 2;
    u16* wqT  = (u16*)p;   p += (size_t)1024 * 1024 * 2;   // wq/wk/wv contiguous -> [3072][1024]
    u16* wkT  = (u16*)p;   p += (size_t)1024 * 1024 * 2;
    u16* wvT  = (u16*)p;   p += (size_t)1024 * 1024 * 2;
    u16* woT  = (u16*)p;   p += (size_t)1024 * 1024 * 2;
    u16* w1T  = (u16*)p;   p += (size_t)1024 * 4096 * 2;
    u16* w2T  = (u16*)p;   p += (size_t)4096 * 1024 * 2;
    u16* whT  = (u16*)p;   p += (size_t)1024 * 256 * 2;

    const dim3 tb(32, 8);
    embed_k<<<8192, 256, 0, stream>>>(idx, tok, pos, x);
    for (int l = 0; l < 6; ++l) {
        transpose_k<<<dim3(32, 32),  tb, 0, stream>>>(Wq + (size_t)l * 1048576, wqT, 1024, 1024);
        transpose_k<<<dim3(32, 32),  tb, 0, stream>>>(Wk + (size_t)l * 1048576, wkT, 1024, 1024);
        transpose_k<<<dim3(32, 32),  tb, 0, stream>>>(Wv + (size_t)l * 1048576, wvT, 1024, 1024);
        transpose_k<<<dim3(32, 32),  tb, 0, stream>>>(Wo + (size_t)l * 1048576, woT, 1024, 1024);
        transpose_k<<<dim3(128, 32), tb, 0, stream>>>(W1 + (size_t)l * 4194304, w1T, 1024, 4096);
        transpose_k<<<dim3(32, 128), tb, 0, stream>>>(W2 + (size_t)l * 4194304, w2T, 4096, 1024);

        ln_k<<<8192, 256, 0, stream>>>(x, ln1g + l * 1024, ln1b + l * 1024, h);
        gemm_bt<0><<<1536, 256, 0, stream>>>(h, wqT, nullptr, nullptr, qkv, nullptr, 3072, 1024, 24);
        attn_mfma_k<<<dim3(8, 128), 256, 0, stream>>>(qkv, ab);
        gemm_bt<1><<<512,  256, 0, stream>>>(ab, woT, bo + l * 1024, x, nullptr, nullptr, 1024, 1024, 8);
        ln_k<<<8192, 256, 0, stream>>>(x, ln2g + l * 1024, ln2b + l * 1024, h);
        gemm_bt<2><<<2048, 256, 0, stream>>>(h, w1T, b1 + l * 4096, nullptr, fb, nullptr, 4096, 1024, 32);
        gemm_bt<1><<<512,  256, 0, stream>>>(fb, w2T, b2 + l * 1024, x, nullptr, nullptr, 1024, 4096, 8);
    }
    transpose_k<<<dim3(8, 32), tb, 0, stream>>>(Wh, whT, 1024, 256);
    ln_k<<<8192, 256, 0, stream>>>(x, lnfg, lnfb, h);
    gemm_bt<3><<<128, 256, 0, stream>>>(h, whT, bh, nullptr, nullptr, (float*)d_out, 256, 1024, 2);
}